// Round 1
// baseline (4738.198 us; speedup 1.0000x reference)
//
#include <hip/hip_runtime.h>
#include <hip/hip_bf16.h>

#define NN 100000
#define CC 25000
#define EE 1000000
#define DD 64
#define BN_EPS 1e-5f

// ---------------------------------------------------------------------------
// fill
__global__ void fill_kernel(float* __restrict__ p, float v, int n) {
    int i = blockIdx.x * blockDim.x + threadIdx.x;
    if (i < n) p[i] = v;
}

// deg[col[e]] += 1
__global__ void deg_kernel(const int* __restrict__ col, float* __restrict__ deg, int E) {
    int e = blockIdx.x * blockDim.x + threadIdx.x;
    if (e < E) atomicAdd(&deg[col[e]], 1.0f);
}

__global__ void rsqrt_kernel(float* __restrict__ d, int n) {
    int i = blockIdx.x * blockDim.x + threadIdx.x;
    if (i < n) d[i] = rsqrtf(d[i]);
}

// ---------------------------------------------------------------------------
// Y[M,64] = op(X[M,64] @ W[64,64])
// GATHER: X row r is X[idx[r]]
// SCALE : multiply row by scale[r] (dinv)
// BIAS  : add bias[c]
// RELU  : relu
// DUAL  : also write Y2 (same values) -- used as scatter accumulator init
template <bool GATHER, bool SCALE, bool BIAS, bool RELU, bool DUAL>
__global__ __launch_bounds__(256) void mm64_kernel(
    const float* __restrict__ X, const int* __restrict__ idx,
    const float* __restrict__ W, const float* __restrict__ bias,
    const float* __restrict__ scale,
    float* __restrict__ Y, float* __restrict__ Y2, int M)
{
    __shared__ float Ws[64 * 64];
    __shared__ float Xs[64 * 64];

    const int tid = threadIdx.x;
    const int rowBase = blockIdx.x * 64;

    // load W (4096 floats) as float4
    {
        const float4* Wv = (const float4*)W;
        float4* Wsv = (float4*)Ws;
        #pragma unroll
        for (int i = tid; i < 1024; i += 256) Wsv[i] = Wv[i];
    }
    // load X tile (64 rows x 64)
    {
        const float4* Xv = (const float4*)X;
        float4* Xsv = (float4*)Xs;
        #pragma unroll
        for (int i = tid; i < 1024; i += 256) {
            int r = i >> 4, c4 = i & 15;
            int gr = rowBase + r;
            float4 v = make_float4(0.f, 0.f, 0.f, 0.f);
            if (gr < M) {
                int sr = GATHER ? idx[gr] : gr;
                v = Xv[(size_t)sr * 16 + c4];
            }
            Xsv[r * 16 + c4] = v;
        }
    }
    __syncthreads();

    const int c = tid & 63;
    const int rg = tid >> 6;

    float acc[16];
    #pragma unroll
    for (int i = 0; i < 16; i++) acc[i] = 0.f;

    #pragma unroll 8
    for (int k = 0; k < 64; k++) {
        float w = Ws[k * 64 + c];
        #pragma unroll
        for (int i = 0; i < 16; i++)
            acc[i] = fmaf(Xs[(rg * 16 + i) * 64 + k], w, acc[i]);
    }

    #pragma unroll
    for (int i = 0; i < 16; i++) {
        int gr = rowBase + rg * 16 + i;
        if (gr < M) {
            float v = acc[i];
            if (SCALE) v *= scale[gr];
            if (BIAS)  v += bias[c];
            if (RELU)  v = fmaxf(v, 0.f);
            Y[(size_t)gr * 64 + c] = v;
            if (DUAL) Y2[(size_t)gr * 64 + c] = v;
        }
    }
}

// ---------------------------------------------------------------------------
// accum[col[e]] += g[row[e]]   (16 threads per edge, float4 each)
__global__ void edge_scatter_kernel(const int* __restrict__ row, const int* __restrict__ col,
                                    const float* __restrict__ g, float* __restrict__ acc, int E)
{
    int t = blockIdx.x * blockDim.x + threadIdx.x;
    int e = t >> 4, q = t & 15;
    if (e < E) {
        int r = row[e], cc = col[e];
        float4 v = ((const float4*)g)[(size_t)r * 16 + q];
        float* dst = acc + (size_t)cc * 64 + q * 4;
        atomicAdd(dst + 0, v.x);
        atomicAdd(dst + 1, v.y);
        atomicAdd(dst + 2, v.z);
        atomicAdd(dst + 3, v.w);
    }
}

// acc[cl[n]] += X[n]
__global__ void pool_scatter_kernel(const int* __restrict__ cl, const float* __restrict__ X,
                                    float* __restrict__ acc, int Nn)
{
    int t = blockIdx.x * blockDim.x + threadIdx.x;
    int n = t >> 4, q = t & 15;
    if (n < Nn) {
        int cc = cl[n];
        float4 v = ((const float4*)X)[(size_t)n * 16 + q];
        float* dst = acc + (size_t)cc * 64 + q * 4;
        atomicAdd(dst + 0, v.x);
        atomicAdd(dst + 1, v.y);
        atomicAdd(dst + 2, v.z);
        atomicAdd(dst + 3, v.w);
    }
}

// acc[i] = (relu?) (acc[i]*dinv[row] + bias[col])
__global__ void finalize_kernel(float* __restrict__ acc, const float* __restrict__ dinv,
                                const float* __restrict__ bias, int M, int relu)
{
    int i = blockIdx.x * blockDim.x + threadIdx.x;
    if (i < M * 64) {
        int r = i >> 6, cc = i & 63;
        float v = acc[i] * dinv[r] + bias[cc];
        if (relu) v = fmaxf(v, 0.f);
        acc[i] = v;
    }
}

// ---------------------------------------------------------------------------
// column sums / sumsq -> stats[0..63] = sum, stats[64..127] = sumsq
__global__ __launch_bounds__(256) void bn_stats_kernel(const float* __restrict__ H,
                                                       float* __restrict__ stats, int M)
{
    const int tid = threadIdx.x;
    const int c = tid & 63;
    const int rg = tid >> 6;
    float s = 0.f, s2 = 0.f;
    for (int r = blockIdx.x * 4 + rg; r < M; r += gridDim.x * 4) {
        float v = H[(size_t)r * 64 + c];
        s += v;
        s2 += v * v;
    }
    __shared__ float sh1[256], sh2[256];
    sh1[tid] = s; sh2[tid] = s2;
    __syncthreads();
    if (tid < 128) { sh1[tid] += sh1[tid + 128]; sh2[tid] += sh2[tid + 128]; }
    __syncthreads();
    if (tid < 64) {
        float a = sh1[tid] + sh1[tid + 64];
        float b = sh2[tid] + sh2[tid + 64];
        atomicAdd(&stats[tid], a);
        atomicAdd(&stats[64 + tid], b);
    }
}

// Y = relu(gamma*(H-mean)*rsqrt(var+eps)+beta)
__global__ void bn_apply_kernel(const float* __restrict__ H, float* __restrict__ Y,
                                const float* __restrict__ stats,
                                const float* __restrict__ gamma, const float* __restrict__ beta,
                                int total, float invM)
{
    int i = blockIdx.x * blockDim.x + threadIdx.x;
    if (i < total) {
        int cc = i & 63;
        float mean = stats[cc] * invM;
        float var = stats[64 + cc] * invM - mean * mean;
        float v = gamma[cc] * (H[i] - mean) * rsqrtf(var + BN_EPS) + beta[cc];
        Y[i] = fmaxf(v, 0.f);
    }
}

// ---------------------------------------------------------------------------
extern "C" void kernel_launch(void* const* d_in, const int* in_sizes, int n_in,
                              void* d_out, int out_size, void* d_ws, size_t ws_size,
                              hipStream_t stream)
{
    const float* x     = (const float*)d_in[0];
    const int*   ei    = (const int*)  d_in[1];
    const int*   scl   = (const int*)  d_in[2];
    const float* cw    = (const float*)d_in[3];
    const float* cb    = (const float*)d_in[4];
    const float* pw    = (const float*)d_in[5];
    const float* pb    = (const float*)d_in[6];
    const float* gamma = (const float*)d_in[7];
    const float* beta  = (const float*)d_in[8];
    float* out = (float*)d_out;

    const int N = NN, C = CC, E = EE;
    const int* row = ei;
    const int* col = ei + E;

    float* A    = (float*)d_ws;
    float* B    = A + (size_t)N * 64;
    float* Cb   = B + (size_t)N * 64;
    float* cb0  = Cb + (size_t)N * 64;
    float* cb1  = cb0 + (size_t)C * 64;
    float* dinv = cb1 + (size_t)C * 64;
    float* stats = dinv + N;

    const int TB = 256;
    dim3 blk(TB);

    // degree -> dinv
    fill_kernel<<<(N + TB - 1) / TB, blk, 0, stream>>>(dinv, 1.0f, N);
    deg_kernel<<<(E + TB - 1) / TB, blk, 0, stream>>>(col, dinv, E);
    rsqrt_kernel<<<(N + TB - 1) / TB, blk, 0, stream>>>(dinv, N);

    auto conv = [&](const float* xin, float* g, float* accum, const float* W,
                    const float* b, bool relu) {
        mm64_kernel<false, true, false, false, true>
            <<<(N + 63) / 64, blk, 0, stream>>>(xin, nullptr, W, nullptr, dinv, g, accum, N);
        edge_scatter_kernel<<<(E * 16 + TB - 1) / TB, blk, 0, stream>>>(row, col, g, accum, E);
        finalize_kernel<<<(N * 64 + TB - 1) / TB, blk, 0, stream>>>(accum, dinv, b, N, relu ? 1 : 0);
    };

    // conv 0, 1
    conv(x, A, B, cw + 0 * 4096, cb + 0 * 64, true);
    conv(B, A, Cb, cw + 1 * 4096, cb + 1 * 64, true);

    // pool down: nodes -> clusters
    fill_kernel<<<(C * 64 + TB - 1) / TB, blk, 0, stream>>>(cb0, 0.f, C * 64);
    pool_scatter_kernel<<<(N * 16 + TB - 1) / TB, blk, 0, stream>>>(scl, Cb, cb0, N);
    mm64_kernel<false, false, true, true, false>
        <<<(C + 63) / 64, blk, 0, stream>>>(cb0, nullptr, pw, pb, nullptr, cb1, nullptr, C);
    fill_kernel<<<1, 128, 0, stream>>>(stats, 0.f, 128);
    bn_stats_kernel<<<512, blk, 0, stream>>>(cb1, stats, C);
    bn_apply_kernel<<<(C * 64 + TB - 1) / TB, blk, 0, stream>>>(cb1, cb0, stats, gamma, beta,
                                                                C * 64, 1.0f / C);

    // pool up: clusters -> nodes (gather fused into matmul)
    mm64_kernel<true, false, true, true, false>
        <<<(N + 63) / 64, blk, 0, stream>>>(cb0, scl, pw + 4096, pb + 64, nullptr, B, nullptr, N);
    fill_kernel<<<1, 128, 0, stream>>>(stats, 0.f, 128);
    bn_stats_kernel<<<512, blk, 0, stream>>>(B, stats, N);
    bn_apply_kernel<<<(N * 64 + TB - 1) / TB, blk, 0, stream>>>(B, A, stats, gamma + 64, beta + 64,
                                                                N * 64, 1.0f / N);

    // conv 2, 3, 4
    conv(A, B, Cb, cw + 2 * 4096, cb + 2 * 64, true);
    conv(Cb, B, A, cw + 3 * 4096, cb + 3 * 64, true);
    conv(A, B, out, cw + 4 * 4096, cb + 4 * 64, false);
}

// Round 2
// 701.861 us; speedup vs baseline: 6.7509x; 6.7509x over previous
//
#include <hip/hip_runtime.h>
#include <hip/hip_bf16.h>

#define NN 100000
#define CC 25000
#define EE 1000000
#define DD 64
#define BN_EPS 1e-5f

// ---------------------------------------------------------------------------
__global__ void fill_f_kernel(float* __restrict__ p, float v, int n) {
    int i = blockIdx.x * blockDim.x + threadIdx.x;
    if (i < n) p[i] = v;
}
__global__ void fill_i_kernel(int* __restrict__ p, int v, int n) {
    int i = blockIdx.x * blockDim.x + threadIdx.x;
    if (i < n) p[i] = v;
}

// deg[idx[e]] += 1 (int histogram)
__global__ void hist_kernel(const int* __restrict__ idx, int* __restrict__ deg, int n) {
    int e = blockIdx.x * blockDim.x + threadIdx.x;
    if (e < n) atomicAdd(&deg[idx[e]], 1);
}

// dinv = rsqrt(deg + 1)   (+1 = self loop)
__global__ void dinv_kernel(const int* __restrict__ deg, float* __restrict__ dinv, int n) {
    int i = blockIdx.x * blockDim.x + threadIdx.x;
    if (i < n) dinv[i] = rsqrtf((float)(deg[i] + 1));
}

// ---------------------------------------------------------------------------
// exclusive scan (3-kernel): blockwise scan (1024 elems/block) -> scan of
// block sums (single block, <=256 blocks) -> add offsets + copy to cursor
__global__ __launch_bounds__(256) void scan_block_kernel(const int* __restrict__ in,
                                                         int* __restrict__ out,
                                                         int* __restrict__ bsum, int n) {
    __shared__ int sh[256];
    const int tid = threadIdx.x;
    const int base = blockIdx.x * 1024 + tid * 4;
    int v0 = 0, v1 = 0, v2 = 0, v3 = 0;
    if (base + 0 < n) v0 = in[base + 0];
    if (base + 1 < n) v1 = in[base + 1];
    if (base + 2 < n) v2 = in[base + 2];
    if (base + 3 < n) v3 = in[base + 3];
    int s = v0 + v1 + v2 + v3;
    sh[tid] = s;
    __syncthreads();
    for (int off = 1; off < 256; off <<= 1) {
        int t = (tid >= off) ? sh[tid - off] : 0;
        __syncthreads();
        sh[tid] += t;
        __syncthreads();
    }
    int excl = sh[tid] - s;
    if (tid == 255) bsum[blockIdx.x] = sh[255];
    if (base + 0 < n) out[base + 0] = excl;
    if (base + 1 < n) out[base + 1] = excl + v0;
    if (base + 2 < n) out[base + 2] = excl + v0 + v1;
    if (base + 3 < n) out[base + 3] = excl + v0 + v1 + v2;
}

__global__ __launch_bounds__(256) void scan_top_kernel(int* __restrict__ bsum, int nb) {
    __shared__ int sh[256];
    const int tid = threadIdx.x;
    int v = (tid < nb) ? bsum[tid] : 0;
    sh[tid] = v;
    __syncthreads();
    for (int off = 1; off < 256; off <<= 1) {
        int t = (tid >= off) ? sh[tid - off] : 0;
        __syncthreads();
        sh[tid] += t;
        __syncthreads();
    }
    if (tid < nb) bsum[tid] = sh[tid] - v;
}

__global__ __launch_bounds__(256) void scan_add_kernel(int* __restrict__ p, int* __restrict__ cursor,
                                                       const int* __restrict__ bsum, int n, int total) {
    const int base = blockIdx.x * 1024;
    const int off = bsum[blockIdx.x];
    for (int j = threadIdx.x; j < 1024; j += 256) {
        int i = base + j;
        if (i < n) { int v = p[i] + off; p[i] = v; cursor[i] = v; }
    }
    if (blockIdx.x == 0 && threadIdx.x == 0) p[n] = total;
}

// csr_src[pos++] = srcval per destination bucket
__global__ void scatter_edges_kernel(const int* __restrict__ row, const int* __restrict__ col,
                                     int* __restrict__ cursor, int* __restrict__ dst, int E) {
    int e = blockIdx.x * blockDim.x + threadIdx.x;
    if (e < E) { int p = atomicAdd(&cursor[col[e]], 1); dst[p] = row[e]; }
}
__global__ void scatter_iota_kernel(const int* __restrict__ cl,
                                    int* __restrict__ cursor, int* __restrict__ dst, int n) {
    int i = blockIdx.x * blockDim.x + threadIdx.x;
    if (i < n) { int p = atomicAdd(&cursor[cl[i]], 1); dst[p] = i; }
}

// ---------------------------------------------------------------------------
// Y[M,64] = op(X[M,64] @ W[64,64])
template <bool GATHER, bool SCALE, bool BIAS, bool RELU>
__global__ __launch_bounds__(256) void mm64_kernel(
    const float* __restrict__ X, const int* __restrict__ idx,
    const float* __restrict__ W, const float* __restrict__ bias,
    const float* __restrict__ scale,
    float* __restrict__ Y, int M)
{
    __shared__ float Ws[64 * 64];
    __shared__ float Xs[64 * 64];

    const int tid = threadIdx.x;
    const int rowBase = blockIdx.x * 64;

    {
        const float4* Wv = (const float4*)W;
        float4* Wsv = (float4*)Ws;
        #pragma unroll
        for (int i = tid; i < 1024; i += 256) Wsv[i] = Wv[i];
    }
    {
        const float4* Xv = (const float4*)X;
        float4* Xsv = (float4*)Xs;
        #pragma unroll
        for (int i = tid; i < 1024; i += 256) {
            int r = i >> 4, c4 = i & 15;
            int gr = rowBase + r;
            float4 v = make_float4(0.f, 0.f, 0.f, 0.f);
            if (gr < M) {
                int sr = GATHER ? idx[gr] : gr;
                v = Xv[(size_t)sr * 16 + c4];
            }
            Xsv[r * 16 + c4] = v;
        }
    }
    __syncthreads();

    const int c = tid & 63;
    const int rg = tid >> 6;

    float acc[16];
    #pragma unroll
    for (int i = 0; i < 16; i++) acc[i] = 0.f;

    #pragma unroll 8
    for (int k = 0; k < 64; k++) {
        float w = Ws[k * 64 + c];
        #pragma unroll
        for (int i = 0; i < 16; i++)
            acc[i] = fmaf(Xs[(rg * 16 + i) * 64 + k], w, acc[i]);
    }

    #pragma unroll
    for (int i = 0; i < 16; i++) {
        int gr = rowBase + rg * 16 + i;
        if (gr < M) {
            float v = acc[i];
            if (SCALE) v *= scale[gr];
            if (BIAS)  v += bias[c];
            if (RELU)  v = fmaxf(v, 0.f);
            Y[(size_t)gr * 64 + c] = v;
        }
    }
}

// ---------------------------------------------------------------------------
// CSR gather-aggregation: one wave per destination node.
// out[n][c] = op( [dinv[n]*] ( [g[n][c] +] sum_{i in rowptr[n]..} g[src[i]][c] ) [+ bias[c]] )
template <bool SELF, bool SCALE, bool BIAS>
__global__ __launch_bounds__(256) void csr_agg_kernel(
    const int* __restrict__ rowptr, const int* __restrict__ src,
    const float* __restrict__ g, const float* __restrict__ dinv,
    const float* __restrict__ bias, float* __restrict__ out, int M, int relu)
{
    const int node = blockIdx.x * 4 + (threadIdx.x >> 6);
    if (node >= M) return;
    const int c = threadIdx.x & 63;

    float s = SELF ? g[(size_t)node * 64 + c] : 0.f;
    const int pb = rowptr[node], pe = rowptr[node + 1];
    int i = pb;
    for (; i + 4 <= pe; i += 4) {
        int r0 = src[i], r1 = src[i + 1], r2 = src[i + 2], r3 = src[i + 3];
        float a0 = g[(size_t)r0 * 64 + c];
        float a1 = g[(size_t)r1 * 64 + c];
        float a2 = g[(size_t)r2 * 64 + c];
        float a3 = g[(size_t)r3 * 64 + c];
        s += (a0 + a1) + (a2 + a3);
    }
    for (; i < pe; i++) s += g[(size_t)src[i] * 64 + c];

    float v = s;
    if (SCALE) v *= dinv[node];
    if (BIAS)  v += bias[c];
    if (relu)  v = fmaxf(v, 0.f);
    out[(size_t)node * 64 + c] = v;
}

// ---------------------------------------------------------------------------
__global__ __launch_bounds__(256) void bn_stats_kernel(const float* __restrict__ H,
                                                       float* __restrict__ stats, int M)
{
    const int tid = threadIdx.x;
    const int c = tid & 63;
    const int rg = tid >> 6;
    float s = 0.f, s2 = 0.f;
    for (int r = blockIdx.x * 4 + rg; r < M; r += gridDim.x * 4) {
        float v = H[(size_t)r * 64 + c];
        s += v;
        s2 += v * v;
    }
    __shared__ float sh1[256], sh2[256];
    sh1[tid] = s; sh2[tid] = s2;
    __syncthreads();
    if (tid < 128) { sh1[tid] += sh1[tid + 128]; sh2[tid] += sh2[tid + 128]; }
    __syncthreads();
    if (tid < 64) {
        float a = sh1[tid] + sh1[tid + 64];
        float b = sh2[tid] + sh2[tid + 64];
        atomicAdd(&stats[tid], a);
        atomicAdd(&stats[64 + tid], b);
    }
}

__global__ void bn_apply_kernel(const float* __restrict__ H, float* __restrict__ Y,
                                const float* __restrict__ stats,
                                const float* __restrict__ gamma, const float* __restrict__ beta,
                                int total, float invM)
{
    int i = blockIdx.x * blockDim.x + threadIdx.x;
    if (i < total) {
        int cc = i & 63;
        float mean = stats[cc] * invM;
        float var = stats[64 + cc] * invM - mean * mean;
        float v = gamma[cc] * (H[i] - mean) * rsqrtf(var + BN_EPS) + beta[cc];
        Y[i] = fmaxf(v, 0.f);
    }
}

// ---------------------------------------------------------------------------
extern "C" void kernel_launch(void* const* d_in, const int* in_sizes, int n_in,
                              void* d_out, int out_size, void* d_ws, size_t ws_size,
                              hipStream_t stream)
{
    const float* x     = (const float*)d_in[0];
    const int*   ei    = (const int*)  d_in[1];
    const int*   scl   = (const int*)  d_in[2];
    const float* cw    = (const float*)d_in[3];
    const float* cb    = (const float*)d_in[4];
    const float* pw    = (const float*)d_in[5];
    const float* pb    = (const float*)d_in[6];
    const float* gamma = (const float*)d_in[7];
    const float* beta  = (const float*)d_in[8];
    float* out = (float*)d_out;

    const int N = NN, C = CC, E = EE;
    const int* row = ei;
    const int* col = ei + E;

    // ---- workspace carve-up (all 16B-aligned sizes) ----
    char* w = (char*)d_ws;
    float* A     = (float*)w;                 w += (size_t)N * 64 * 4;
    float* B     = (float*)w;                 w += (size_t)N * 64 * 4;
    float* Cb    = (float*)w;                 w += (size_t)N * 64 * 4;
    float* cb0   = (float*)w;                 w += (size_t)C * 64 * 4;
    float* cb1   = (float*)w;                 w += (size_t)C * 64 * 4;
    float* dinv  = (float*)w;                 w += (size_t)N * 4;
    float* stats = (float*)w;                 w += 128 * 4;
    int* deg_i   = (int*)w;                   w += (size_t)N * 4;
    int* rowptr  = (int*)w;                   w += (size_t)(N + 4) * 4;
    int* cursor  = (int*)w;                   w += (size_t)N * 4;
    int* csrc    = (int*)w;                   w += (size_t)E * 4;
    int* cdeg    = (int*)w;                   w += (size_t)C * 4;
    int* crowptr = (int*)w;                   w += (size_t)(C + 4) * 4;
    int* ccursor = (int*)w;                   w += (size_t)C * 4;
    int* cnsrc   = (int*)w;                   w += (size_t)N * 4;
    int* bsum    = (int*)w;                   w += 256 * 4;

    const int TB = 256;
    dim3 blk(TB);
    const int NB_N = (N + 1023) / 1024;   // 98
    const int NB_C = (C + 1023) / 1024;   // 25

    // ---- build CSR (edges by dst) + cluster CSR (nodes by cluster) ----
    fill_i_kernel<<<(N + TB - 1) / TB, blk, 0, stream>>>(deg_i, 0, N);
    fill_i_kernel<<<(C + TB - 1) / TB, blk, 0, stream>>>(cdeg, 0, C);
    hist_kernel<<<(E + TB - 1) / TB, blk, 0, stream>>>(col, deg_i, E);
    hist_kernel<<<(N + TB - 1) / TB, blk, 0, stream>>>(scl, cdeg, N);
    dinv_kernel<<<(N + TB - 1) / TB, blk, 0, stream>>>(deg_i, dinv, N);

    scan_block_kernel<<<NB_N, blk, 0, stream>>>(deg_i, rowptr, bsum, N);
    scan_top_kernel<<<1, blk, 0, stream>>>(bsum, NB_N);
    scan_add_kernel<<<NB_N, blk, 0, stream>>>(rowptr, cursor, bsum, N, E);
    scatter_edges_kernel<<<(E + TB - 1) / TB, blk, 0, stream>>>(row, col, cursor, csrc, E);

    scan_block_kernel<<<NB_C, blk, 0, stream>>>(cdeg, crowptr, bsum, C);
    scan_top_kernel<<<1, blk, 0, stream>>>(bsum, NB_C);
    scan_add_kernel<<<NB_C, blk, 0, stream>>>(crowptr, ccursor, bsum, C, N);
    scatter_iota_kernel<<<(N + TB - 1) / TB, blk, 0, stream>>>(scl, ccursor, cnsrc, N);

    // ---- pipeline ----
    auto conv = [&](const float* xin, float* g, float* yout, const float* W,
                    const float* b, bool relu) {
        mm64_kernel<false, true, false, false>
            <<<(N + 63) / 64, blk, 0, stream>>>(xin, nullptr, W, nullptr, dinv, g, N);
        csr_agg_kernel<true, true, true>
            <<<(N + 3) / 4, blk, 0, stream>>>(rowptr, csrc, g, dinv, b, yout, N, relu ? 1 : 0);
    };

    // conv 0, 1
    conv(x, A, B, cw + 0 * 4096, cb + 0 * 64, true);
    conv(B, A, Cb, cw + 1 * 4096, cb + 1 * 64, true);

    // pool down: nodes -> clusters (CSR gather), Linear+ReLU, BN+ReLU
    csr_agg_kernel<false, false, false>
        <<<(C + 3) / 4, blk, 0, stream>>>(crowptr, cnsrc, Cb, nullptr, nullptr, cb0, C, 0);
    mm64_kernel<false, false, true, true>
        <<<(C + 63) / 64, blk, 0, stream>>>(cb0, nullptr, pw, pb, nullptr, cb1, C);
    fill_f_kernel<<<1, 128, 0, stream>>>(stats, 0.f, 128);
    bn_stats_kernel<<<512, blk, 0, stream>>>(cb1, stats, C);
    bn_apply_kernel<<<(C * 64 + TB - 1) / TB, blk, 0, stream>>>(cb1, cb0, stats, gamma, beta,
                                                                C * 64, 1.0f / C);

    // pool up: clusters -> nodes (gather fused into matmul), BN+ReLU
    mm64_kernel<true, false, true, true>
        <<<(N + 63) / 64, blk, 0, stream>>>(cb0, scl, pw + 4096, pb + 64, nullptr, B, N);
    fill_f_kernel<<<1, 128, 0, stream>>>(stats, 0.f, 128);
    bn_stats_kernel<<<512, blk, 0, stream>>>(B, stats, N);
    bn_apply_kernel<<<(N * 64 + TB - 1) / TB, blk, 0, stream>>>(B, A, stats, gamma + 64, beta + 64,
                                                                N * 64, 1.0f / N);

    // conv 2, 3, 4
    conv(A, B, Cb, cw + 2 * 4096, cb + 2 * 64, true);
    conv(Cb, B, A, cw + 3 * 4096, cb + 3 * 64, true);
    conv(A, B, out, cw + 4 * 4096, cb + 4 * 64, false);
}

// Round 3
// 592.819 us; speedup vs baseline: 7.9927x; 1.1839x over previous
//
#include <hip/hip_runtime.h>
#include <hip/hip_bf16.h>

#define NN 100000
#define CC 25000
#define EE 1000000
#define BN_EPS 1e-5f

typedef unsigned int u32;
typedef unsigned short u16;

// ---------------------------------------------------------------------------
// bf16 helpers (RNE)
__device__ __forceinline__ float lo2f(u32 p) { return __uint_as_float(p << 16); }
__device__ __forceinline__ float hi2f(u32 p) { return __uint_as_float(p & 0xFFFF0000u); }
__device__ __forceinline__ u16 f2bf(float f) {
    u32 u = __float_as_uint(f);
    u32 r = u + 0x7FFFu + ((u >> 16) & 1u);
    return (u16)(r >> 16);
}
__device__ __forceinline__ u32 pack2(float a, float b) {
    return (u32)f2bf(a) | ((u32)f2bf(b) << 16);
}

// ---------------------------------------------------------------------------
__global__ void fill_f_kernel(float* __restrict__ p, float v, int n) {
    int i = blockIdx.x * blockDim.x + threadIdx.x;
    if (i < n) p[i] = v;
}
__global__ void fill_i_kernel(int* __restrict__ p, int v, int n) {
    int i = blockIdx.x * blockDim.x + threadIdx.x;
    if (i < n) p[i] = v;
}

__global__ void hist_kernel(const int* __restrict__ idx, int* __restrict__ deg, int n) {
    int e = blockIdx.x * blockDim.x + threadIdx.x;
    if (e < n) atomicAdd(&deg[idx[e]], 1);
}

__global__ void dinv_kernel(const int* __restrict__ deg, float* __restrict__ dinv, int n) {
    int i = blockIdx.x * blockDim.x + threadIdx.x;
    if (i < n) dinv[i] = rsqrtf((float)(deg[i] + 1));
}

// ---------------------------------------------------------------------------
// exclusive scan (3-kernel)
__global__ __launch_bounds__(256) void scan_block_kernel(const int* __restrict__ in,
                                                         int* __restrict__ out,
                                                         int* __restrict__ bsum, int n) {
    __shared__ int sh[256];
    const int tid = threadIdx.x;
    const int base = blockIdx.x * 1024 + tid * 4;
    int v0 = 0, v1 = 0, v2 = 0, v3 = 0;
    if (base + 0 < n) v0 = in[base + 0];
    if (base + 1 < n) v1 = in[base + 1];
    if (base + 2 < n) v2 = in[base + 2];
    if (base + 3 < n) v3 = in[base + 3];
    int s = v0 + v1 + v2 + v3;
    sh[tid] = s;
    __syncthreads();
    for (int off = 1; off < 256; off <<= 1) {
        int t = (tid >= off) ? sh[tid - off] : 0;
        __syncthreads();
        sh[tid] += t;
        __syncthreads();
    }
    int excl = sh[tid] - s;
    if (tid == 255) bsum[blockIdx.x] = sh[255];
    if (base + 0 < n) out[base + 0] = excl;
    if (base + 1 < n) out[base + 1] = excl + v0;
    if (base + 2 < n) out[base + 2] = excl + v0 + v1;
    if (base + 3 < n) out[base + 3] = excl + v0 + v1 + v2;
}

__global__ __launch_bounds__(256) void scan_top_kernel(int* __restrict__ bsum, int nb) {
    __shared__ int sh[256];
    const int tid = threadIdx.x;
    int v = (tid < nb) ? bsum[tid] : 0;
    sh[tid] = v;
    __syncthreads();
    for (int off = 1; off < 256; off <<= 1) {
        int t = (tid >= off) ? sh[tid - off] : 0;
        __syncthreads();
        sh[tid] += t;
        __syncthreads();
    }
    if (tid < nb) bsum[tid] = sh[tid] - v;
}

__global__ __launch_bounds__(256) void scan_add_kernel(int* __restrict__ p, int* __restrict__ cursor,
                                                       const int* __restrict__ bsum, int n, int total) {
    const int base = blockIdx.x * 1024;
    const int off = bsum[blockIdx.x];
    for (int j = threadIdx.x; j < 1024; j += 256) {
        int i = base + j;
        if (i < n) { int v = p[i] + off; p[i] = v; cursor[i] = v; }
    }
    if (blockIdx.x == 0 && threadIdx.x == 0) p[n] = total;
}

__global__ void scatter_edges_kernel(const int* __restrict__ row, const int* __restrict__ col,
                                     int* __restrict__ cursor, int* __restrict__ dst, int E) {
    int e = blockIdx.x * blockDim.x + threadIdx.x;
    if (e < E) { int p = atomicAdd(&cursor[col[e]], 1); dst[p] = row[e]; }
}
__global__ void scatter_iota_kernel(const int* __restrict__ cl,
                                    int* __restrict__ cursor, int* __restrict__ dst, int n) {
    int i = blockIdx.x * blockDim.x + threadIdx.x;
    if (i < n) { int p = atomicAdd(&cursor[cl[i]], 1); dst[p] = i; }
}

// ---------------------------------------------------------------------------
// Y[M,64] = op(X[M,64] @ W[64,64]); X bf16 (or fp32 if INF32), Y bf16 (or fp32)
template <bool INF32, bool GATHER, bool SCALE, bool BIAS, bool RELU, bool OUTF32>
__global__ __launch_bounds__(256) void mm64_kernel(
    const void* __restrict__ Xv_, const int* __restrict__ idx,
    const float* __restrict__ W, const float* __restrict__ bias,
    const float* __restrict__ scale,
    void* __restrict__ Yv, int M)
{
    __shared__ float Ws[64 * 64];
    __shared__ float Xs[64 * 64];

    const int tid = threadIdx.x;
    const int rowBase = blockIdx.x * 64;

    {
        const float4* Wv = (const float4*)W;
        float4* Wsv = (float4*)Ws;
        #pragma unroll
        for (int i = tid; i < 1024; i += 256) Wsv[i] = Wv[i];
    }
    if (INF32) {
        const float4* Xv = (const float4*)Xv_;
        float4* Xsv = (float4*)Xs;
        #pragma unroll
        for (int i = tid; i < 1024; i += 256) {
            int r = i >> 4, c4 = i & 15;
            int gr = rowBase + r;
            float4 v = make_float4(0.f, 0.f, 0.f, 0.f);
            if (gr < M) {
                int sr = GATHER ? idx[gr] : gr;
                v = Xv[(size_t)sr * 16 + c4];
            }
            Xsv[r * 16 + c4] = v;
        }
    } else {
        const uint4* Xv = (const uint4*)Xv_;
        #pragma unroll
        for (int i = tid; i < 512; i += 256) {
            int r = i >> 3, u = i & 7;
            int gr = rowBase + r;
            uint4 v = make_uint4(0u, 0u, 0u, 0u);
            if (gr < M) {
                int sr = GATHER ? idx[gr] : gr;
                v = Xv[(size_t)sr * 8 + u];
            }
            float* xp = &Xs[r * 64 + u * 8];
            xp[0] = lo2f(v.x); xp[1] = hi2f(v.x);
            xp[2] = lo2f(v.y); xp[3] = hi2f(v.y);
            xp[4] = lo2f(v.z); xp[5] = hi2f(v.z);
            xp[6] = lo2f(v.w); xp[7] = hi2f(v.w);
        }
    }
    __syncthreads();

    const int c = tid & 63;
    const int rg = tid >> 6;

    float acc[16];
    #pragma unroll
    for (int i = 0; i < 16; i++) acc[i] = 0.f;

    #pragma unroll 8
    for (int k = 0; k < 64; k++) {
        float w = Ws[k * 64 + c];
        #pragma unroll
        for (int i = 0; i < 16; i++)
            acc[i] = fmaf(Xs[(rg * 16 + i) * 64 + k], w, acc[i]);
    }

    #pragma unroll
    for (int i = 0; i < 16; i++) {
        int gr = rowBase + rg * 16 + i;
        if (gr < M) {
            float v = acc[i];
            if (SCALE) v *= scale[gr];
            if (BIAS)  v += bias[c];
            if (RELU)  v = fmaxf(v, 0.f);
            if (OUTF32) ((float*)Yv)[(size_t)gr * 64 + c] = v;
            else        ((u16*)Yv)[(size_t)gr * 64 + c] = f2bf(v);
        }
    }
}

// ---------------------------------------------------------------------------
// CSR gather-aggregation, bf16 rows (32 lanes per node, 2 cols per lane)
template <bool SELF, bool SCALE, bool BIAS, bool RELU, bool OUTF32>
__global__ __launch_bounds__(256) void csr_agg_kernel(
    const int* __restrict__ rowptr, const int* __restrict__ src,
    const u32* __restrict__ g, const float* __restrict__ dinv,
    const float* __restrict__ bias, void* __restrict__ out, int M)
{
    const int node = blockIdx.x * 8 + (threadIdx.x >> 5);
    if (node >= M) return;
    const int c2 = threadIdx.x & 31;

    float s0 = 0.f, s1 = 0.f;
    if (SELF) { u32 p = g[(size_t)node * 32 + c2]; s0 = lo2f(p); s1 = hi2f(p); }

    int i = rowptr[node];
    const int pe = rowptr[node + 1];
    for (; i + 4 <= pe; i += 4) {
        int r0 = src[i], r1 = src[i + 1], r2 = src[i + 2], r3 = src[i + 3];
        u32 p0 = g[(size_t)r0 * 32 + c2];
        u32 p1 = g[(size_t)r1 * 32 + c2];
        u32 p2 = g[(size_t)r2 * 32 + c2];
        u32 p3 = g[(size_t)r3 * 32 + c2];
        s0 += (lo2f(p0) + lo2f(p1)) + (lo2f(p2) + lo2f(p3));
        s1 += (hi2f(p0) + hi2f(p1)) + (hi2f(p2) + hi2f(p3));
    }
    for (; i < pe; i++) {
        u32 p = g[(size_t)src[i] * 32 + c2];
        s0 += lo2f(p); s1 += hi2f(p);
    }

    if (SCALE) { float d = dinv[node]; s0 *= d; s1 *= d; }
    if (BIAS)  { s0 += bias[c2 * 2]; s1 += bias[c2 * 2 + 1]; }
    if (RELU)  { s0 = fmaxf(s0, 0.f); s1 = fmaxf(s1, 0.f); }
    if (OUTF32) ((float2*)out)[(size_t)node * 32 + c2] = make_float2(s0, s1);
    else        ((u32*)out)[(size_t)node * 32 + c2] = pack2(s0, s1);
}

// ---------------------------------------------------------------------------
__global__ __launch_bounds__(256) void bn_stats_kernel(const u32* __restrict__ H,
                                                       float* __restrict__ stats, int M)
{
    const int tid = threadIdx.x;
    const int c2 = tid & 31;
    const int rg = tid >> 5;
    float a0 = 0.f, a1 = 0.f, b0 = 0.f, b1 = 0.f;
    for (int r = blockIdx.x * 8 + rg; r < M; r += gridDim.x * 8) {
        u32 p = H[(size_t)r * 32 + c2];
        float x0 = lo2f(p), x1 = hi2f(p);
        a0 += x0; a1 += x1; b0 += x0 * x0; b1 += x1 * x1;
    }
    __shared__ float s0[256], s1[256], q0[256], q1[256];
    s0[tid] = a0; s1[tid] = a1; q0[tid] = b0; q1[tid] = b1;
    __syncthreads();
    if (tid < 64) {
        int cc2 = tid >> 1, sub = tid & 1;
        const float* sa = sub ? s1 : s0;
        const float* qa = sub ? q1 : q0;
        float a = 0.f, b = 0.f;
        #pragma unroll
        for (int g8 = 0; g8 < 8; g8++) { a += sa[g8 * 32 + cc2]; b += qa[g8 * 32 + cc2]; }
        atomicAdd(&stats[tid], a);
        atomicAdd(&stats[64 + tid], b);
    }
}

__global__ void bn_apply_kernel(const u32* __restrict__ H, u32* __restrict__ Y,
                                const float* __restrict__ stats,
                                const float* __restrict__ gamma, const float* __restrict__ beta,
                                int total32, float invM)
{
    int i = blockIdx.x * blockDim.x + threadIdx.x;
    if (i < total32) {
        int c2 = i & 31;
        float m0 = stats[c2 * 2] * invM,     m1 = stats[c2 * 2 + 1] * invM;
        float v0 = stats[64 + c2 * 2] * invM - m0 * m0;
        float v1 = stats[64 + c2 * 2 + 1] * invM - m1 * m1;
        u32 p = H[i];
        float x0 = gamma[c2 * 2]     * (lo2f(p) - m0) * rsqrtf(v0 + BN_EPS) + beta[c2 * 2];
        float x1 = gamma[c2 * 2 + 1] * (hi2f(p) - m1) * rsqrtf(v1 + BN_EPS) + beta[c2 * 2 + 1];
        Y[i] = pack2(fmaxf(x0, 0.f), fmaxf(x1, 0.f));
    }
}

// ---------------------------------------------------------------------------
extern "C" void kernel_launch(void* const* d_in, const int* in_sizes, int n_in,
                              void* d_out, int out_size, void* d_ws, size_t ws_size,
                              hipStream_t stream)
{
    const float* x     = (const float*)d_in[0];
    const int*   ei    = (const int*)  d_in[1];
    const int*   scl   = (const int*)  d_in[2];
    const float* cw    = (const float*)d_in[3];
    const float* cb    = (const float*)d_in[4];
    const float* pw    = (const float*)d_in[5];
    const float* pb    = (const float*)d_in[6];
    const float* gamma = (const float*)d_in[7];
    const float* beta  = (const float*)d_in[8];
    float* out = (float*)d_out;

    const int N = NN, C = CC, E = EE;
    const int* row = ei;
    const int* col = ei + E;

    // ---- workspace carve-up (keep 16B alignment) ----
    char* w = (char*)d_ws;
    u16* A      = (u16*)w;                 w += (size_t)N * 64 * 2;   // bf16 N x 64
    u16* B      = (u16*)w;                 w += (size_t)N * 64 * 2;
    u16* Cb     = (u16*)w;                 w += (size_t)N * 64 * 2;
    u16* cb0    = (u16*)w;                 w += (size_t)C * 64 * 2;
    u16* cb1    = (u16*)w;                 w += (size_t)C * 64 * 2;
    float* dinv = (float*)w;               w += (size_t)N * 4;
    float* stats = (float*)w;              w += 128 * 4;
    int* deg_i   = (int*)w;                w += (size_t)N * 4;
    int* rowptr  = (int*)w;                w += (size_t)(N + 4) * 4;
    int* cursor  = (int*)w;                w += (size_t)N * 4;
    int* csrc    = (int*)w;                w += (size_t)E * 4;
    int* cdeg    = (int*)w;                w += (size_t)C * 4;
    int* crowptr = (int*)w;                w += (size_t)(C + 4) * 4;
    int* ccursor = (int*)w;                w += (size_t)C * 4;
    int* cnsrc   = (int*)w;                w += (size_t)N * 4;
    int* bsum    = (int*)w;                w += 256 * 4;

    const int TB = 256;
    dim3 blk(TB);
    const int NB_N = (N + 1023) / 1024;
    const int NB_C = (C + 1023) / 1024;

    // ---- build CSR (edges by dst) + cluster CSR (nodes by cluster) ----
    fill_i_kernel<<<(N + TB - 1) / TB, blk, 0, stream>>>(deg_i, 0, N);
    fill_i_kernel<<<(C + TB - 1) / TB, blk, 0, stream>>>(cdeg, 0, C);
    hist_kernel<<<(E + TB - 1) / TB, blk, 0, stream>>>(col, deg_i, E);
    hist_kernel<<<(N + TB - 1) / TB, blk, 0, stream>>>(scl, cdeg, N);
    dinv_kernel<<<(N + TB - 1) / TB, blk, 0, stream>>>(deg_i, dinv, N);

    scan_block_kernel<<<NB_N, blk, 0, stream>>>(deg_i, rowptr, bsum, N);
    scan_top_kernel<<<1, blk, 0, stream>>>(bsum, NB_N);
    scan_add_kernel<<<NB_N, blk, 0, stream>>>(rowptr, cursor, bsum, N, E);
    scatter_edges_kernel<<<(E + TB - 1) / TB, blk, 0, stream>>>(row, col, cursor, csrc, E);

    scan_block_kernel<<<NB_C, blk, 0, stream>>>(cdeg, crowptr, bsum, C);
    scan_top_kernel<<<1, blk, 0, stream>>>(bsum, NB_C);
    scan_add_kernel<<<NB_C, blk, 0, stream>>>(crowptr, ccursor, bsum, C, N);
    scatter_iota_kernel<<<(N + TB - 1) / TB, blk, 0, stream>>>(scl, ccursor, cnsrc, N);

    // ---- pipeline ----
    // conv 0 (fp32 input)
    mm64_kernel<true, false, true, false, false, false>
        <<<(N + 63) / 64, blk, 0, stream>>>(x, nullptr, cw + 0 * 4096, nullptr, dinv, A, N);
    csr_agg_kernel<true, true, true, true, false>
        <<<(N + 7) / 8, blk, 0, stream>>>(rowptr, csrc, (const u32*)A, dinv, cb + 0 * 64, B, N);
    // conv 1
    mm64_kernel<false, false, true, false, false, false>
        <<<(N + 63) / 64, blk, 0, stream>>>(B, nullptr, cw + 1 * 4096, nullptr, dinv, A, N);
    csr_agg_kernel<true, true, true, true, false>
        <<<(N + 7) / 8, blk, 0, stream>>>(rowptr, csrc, (const u32*)A, dinv, cb + 1 * 64, Cb, N);

    // pool down: clusters gather, Linear+ReLU, BN+ReLU
    csr_agg_kernel<false, false, false, false, false>
        <<<(C + 7) / 8, blk, 0, stream>>>(crowptr, cnsrc, (const u32*)Cb, nullptr, nullptr, cb0, C);
    mm64_kernel<false, false, false, true, true, false>
        <<<(C + 63) / 64, blk, 0, stream>>>(cb0, nullptr, pw, pb, nullptr, cb1, C);
    fill_f_kernel<<<1, 128, 0, stream>>>(stats, 0.f, 128);
    bn_stats_kernel<<<512, blk, 0, stream>>>((const u32*)cb1, stats, C);
    bn_apply_kernel<<<(C * 32 + TB - 1) / TB, blk, 0, stream>>>((const u32*)cb1, (u32*)cb0, stats,
                                                                gamma, beta, C * 32, 1.0f / C);

    // pool up: gather fused into matmul, BN+ReLU
    mm64_kernel<false, true, false, true, true, false>
        <<<(N + 63) / 64, blk, 0, stream>>>(cb0, scl, pw + 4096, pb + 64, nullptr, B, N);
    fill_f_kernel<<<1, 128, 0, stream>>>(stats, 0.f, 128);
    bn_stats_kernel<<<512, blk, 0, stream>>>((const u32*)B, stats, N);
    bn_apply_kernel<<<(N * 32 + TB - 1) / TB, blk, 0, stream>>>((const u32*)B, (u32*)A, stats,
                                                                gamma + 64, beta + 64, N * 32, 1.0f / N);

    // conv 2
    mm64_kernel<false, false, true, false, false, false>
        <<<(N + 63) / 64, blk, 0, stream>>>(A, nullptr, cw + 2 * 4096, nullptr, dinv, B, N);
    csr_agg_kernel<true, true, true, true, false>
        <<<(N + 7) / 8, blk, 0, stream>>>(rowptr, csrc, (const u32*)B, dinv, cb + 2 * 64, Cb, N);
    // conv 3
    mm64_kernel<false, false, true, false, false, false>
        <<<(N + 63) / 64, blk, 0, stream>>>(Cb, nullptr, cw + 3 * 4096, nullptr, dinv, B, N);
    csr_agg_kernel<true, true, true, true, false>
        <<<(N + 7) / 8, blk, 0, stream>>>(rowptr, csrc, (const u32*)B, dinv, cb + 3 * 64, A, N);
    // conv 4 (fp32 output, no relu)
    mm64_kernel<false, false, true, false, false, false>
        <<<(N + 63) / 64, blk, 0, stream>>>(A, nullptr, cw + 4 * 4096, nullptr, dinv, B, N);
    csr_agg_kernel<true, true, true, false, true>
        <<<(N + 7) / 8, blk, 0, stream>>>(rowptr, csrc, (const u32*)B, dinv, cb + 4 * 64, out, N);
}